// Round 1
// baseline (115.941 us; speedup 1.0000x reference)
//
#include <hip/hip_runtime.h>
#include <math.h>

// WignerDRotation: out = Z(alpha) * J * Z(beta) * J * Z(gamma) * x, block-diagonal
// over irreps [0]*256 + [1]*256 + [2]*128 + [3]*64, DIM=2112, CH=32, N=1024.
// All copies of the same l share one d x d composite matrix M_l per batch row.

namespace {

constexpr float SQ3_2 = 0.86602540378443864676f;  // sqrt(3)/2
constexpr float S6    = 0.61237243569579452455f;  // sqrt(6)/4
constexpr float S10   = 0.79056941504209483300f;  // sqrt(10)/4
constexpr float S15   = 0.96824583655185422129f;  // sqrt(15)/4

// J_l: real-SH matrix of the y<->z axis swap in the reference's convention
// (Condon-Shortley phase, rows/cols ordered m = -l..l). J = J^T = J^-1.
template<int L> struct JM;
template<> struct JM<1> {
  static constexpr float v[3][3] = {
    { 0.f, -1.f, 0.f},
    {-1.f,  0.f, 0.f},
    { 0.f,  0.f, 1.f}};
};
template<> struct JM<2> {
  static constexpr float v[5][5] = {
    { 0.f, 0.f,  0.f,   -1.f,  0.f},
    { 0.f, 1.f,  0.f,    0.f,  0.f},
    { 0.f, 0.f, -0.5f,   0.f, -SQ3_2},
    {-1.f, 0.f,  0.f,    0.f,  0.f},
    { 0.f, 0.f, -SQ3_2,  0.f,  0.5f}};
};
template<> struct JM<3> {
  static constexpr float v[7][7] = {
    { 0.f, 0.f, 0.f, S10,  0.f,   -S6,  0.f},
    { 0.f, 1.f, 0.f, 0.f,  0.f,    0.f, 0.f},
    { 0.f, 0.f, 0.f, S6,   0.f,    S10, 0.f},
    { S10, 0.f, S6,  0.f,  0.f,    0.f, 0.f},
    { 0.f, 0.f, 0.f, 0.f, -0.25f,  0.f, -S15},
    {-S6,  0.f, S10, 0.f,  0.f,    0.f, 0.f},
    { 0.f, 0.f, 0.f, 0.f, -S15,    0.f, 0.25f}};
};

// Column q of M_l = Zalpha * J * Zbeta * J * Zgamma. Column-local: Z only mixes
// m <-> -m inside the column, so each lane computes one column independently.
// Z[p,s] = cos(p*th)[s==p] - sin(p*th)[s==-p]  (signed m; index = m + L).
template<int L>
__device__ inline void compute_M_col(int q, float al, float be, float ga, float* M) {
  constexpr int D = 2 * L + 1;
  const int mq = q - L;
  float sg, cg;
  sincosf((float)mq * ga, &sg, &cg);
  // v = J * (Zgamma e_q) = cos(mq*g)*J[:,q] + sin(mq*g)*J[:,D-1-q]
  float v[D];
#pragma unroll
  for (int p = 0; p < D; ++p)
    v[p] = cg * JM<L>::v[p][q] + sg * JM<L>::v[p][(D - 1) - q];
  // w = Zbeta * v
  float c1, s1;
  sincosf(be, &s1, &c1);
  float cb[L + 1], sb[L + 1];
  cb[0] = 1.f; sb[0] = 0.f;
  cb[1] = c1;  sb[1] = s1;
#pragma unroll
  for (int k = 2; k <= L; ++k) {  // Chebyshev: cos/sin of k*beta
    cb[k] = 2.f * c1 * cb[k - 1] - cb[k - 2];
    sb[k] = 2.f * c1 * sb[k - 1] - sb[k - 2];
  }
  float w[D];
#pragma unroll
  for (int p = 0; p < D; ++p) {
    const int mp = p - L;
    const int am = mp < 0 ? -mp : mp;
    const float c = cb[am];
    const float s = mp < 0 ? -sb[am] : sb[am];
    w[p] = c * v[p] - s * v[(D - 1) - p];
  }
  // u = J * w  (J entries are compile-time constants, mostly zero)
  float u[D];
#pragma unroll
  for (int p = 0; p < D; ++p) {
    float acc = 0.f;
#pragma unroll
    for (int r = 0; r < D; ++r) acc = fmaf(JM<L>::v[p][r], w[r], acc);
    u[p] = acc;
  }
  // Mcol = Zalpha * u
  sincosf(al, &s1, &c1);
  float ca[L + 1], sa[L + 1];
  ca[0] = 1.f; sa[0] = 0.f;
  ca[1] = c1;  sa[1] = s1;
#pragma unroll
  for (int k = 2; k <= L; ++k) {
    ca[k] = 2.f * c1 * ca[k - 1] - ca[k - 2];
    sa[k] = 2.f * c1 * sa[k - 1] - sa[k - 2];
  }
#pragma unroll
  for (int p = 0; p < D; ++p) {
    const int mp = p - L;
    const int am = mp < 0 ? -mp : mp;
    const float c = ca[am];
    const float s = mp < 0 ? -sa[am] : sa[am];
    M[p * D + q] = c * u[p] - s * u[(D - 1) - p];
  }
}

// One 8-lane group applies M (d x d, in LDS, broadcast reads) to one irrep
// copy: d rows x 32 channels, each lane owns 4 channels (float4).
template<int D>
__device__ inline void apply_block(const float4* __restrict__ inN,
                                   float4* __restrict__ outN,
                                   const float* __restrict__ M, int off, int ch) {
  float4 v[D];
#pragma unroll
  for (int q = 0; q < D; ++q) v[q] = inN[(off + q) * 8 + ch];
#pragma unroll
  for (int p = 0; p < D; ++p) {
    float m = M[p * D];
    float4 a;
    a.x = m * v[0].x; a.y = m * v[0].y; a.z = m * v[0].z; a.w = m * v[0].w;
#pragma unroll
    for (int q = 1; q < D; ++q) {
      m = M[p * D + q];
      a.x = fmaf(m, v[q].x, a.x);
      a.y = fmaf(m, v[q].y, a.y);
      a.z = fmaf(m, v[q].z, a.z);
      a.w = fmaf(m, v[q].w, a.w);
    }
    outN[(off + p) * 8 + ch] = a;
  }
}

__global__ __launch_bounds__(256) void wigner_d_kernel(
    const float* __restrict__ in, const float* __restrict__ alpha,
    const float* __restrict__ beta, const float* __restrict__ gamma,
    float* __restrict__ out) {
  __shared__ float M1[9], M2[25], M3[49];
  const int n = blockIdx.x;
  const int t = threadIdx.x;

  // 15 lanes of wave 0 build the composite matrices (one column each).
  if (t < 19) {
    const float al = alpha[n], be = beta[n], ga = gamma[n];
    if (t < 7)                  compute_M_col<3>(t,      al, be, ga, M3);
    else if (t >= 8 && t < 13)  compute_M_col<2>(t - 8,  al, be, ga, M2);
    else if (t >= 16)           compute_M_col<1>(t - 16, al, be, ga, M1);
  }
  __syncthreads();

  const size_t base = (size_t)n * (2112 * 8);  // float4 units
  const float4* inN = (const float4*)in + base;
  float4* outN = (float4*)out + base;
  const int g = t >> 3;   // group 0..31: one irrep copy per iteration
  const int ch = t & 7;   // float4 lane within the 32-channel row

  // l=0 (rows 0..255): M = 1, pure copy. Copy k = 32j + g; boundaries land on
  // multiples of 32 copies, so every j-iteration is uniform-l across the block.
#pragma unroll
  for (int j = 0; j < 8; ++j) {
    const int r = 32 * j + g;
    outN[r * 8 + ch] = inN[r * 8 + ch];
  }
  // l=1: 256 copies of d=3 at rows 256..1023
  for (int j = 0; j < 8; ++j)
    apply_block<3>(inN, outN, M1, 256 + 3 * (32 * j + g), ch);
  // l=2: 128 copies of d=5 at rows 1024..1663
  for (int j = 0; j < 4; ++j)
    apply_block<5>(inN, outN, M2, 1024 + 5 * (32 * j + g), ch);
  // l=3: 64 copies of d=7 at rows 1664..2111
  for (int j = 0; j < 2; ++j)
    apply_block<7>(inN, outN, M3, 1664 + 7 * (32 * j + g), ch);
}

}  // namespace

extern "C" void kernel_launch(void* const* d_in, const int* in_sizes, int n_in,
                              void* d_out, int out_size, void* d_ws, size_t ws_size,
                              hipStream_t stream) {
  const float* in    = (const float*)d_in[0];
  const float* alpha = (const float*)d_in[1];
  const float* beta  = (const float*)d_in[2];
  const float* gamma = (const float*)d_in[3];
  float* out = (float*)d_out;
  const int n_batch = in_sizes[1];  // 1024
  wigner_d_kernel<<<n_batch, 256, 0, stream>>>(in, alpha, beta, gamma, out);
}